// Round 15
// baseline (1643.348 us; speedup 1.0000x reference)
//
#include <hip/hip_runtime.h>
#include <hip/hip_cooperative_groups.h>
#include <hip/hip_bf16.h>
#include <math.h>

namespace cg = cooperative_groups;

#define B_ 2
#define S_ 2048
#define H_ 512
#define NH_ 8
#define HD_ 64
#define L_ 4
#define INTER_ 2048
#define W1_ 32
#define M_ (B_*S_)   // 4096

typedef __attribute__((ext_vector_type(8))) short short8v;
typedef __attribute__((ext_vector_type(4))) float f32x4;

__device__ __forceinline__ float b2f(ushort u){ return __uint_as_float(((unsigned)u)<<16); }
__device__ __forceinline__ ushort f2b(float f){
  unsigned u = __float_as_uint(f);
  unsigned r = (u + 0x7fffu + ((u>>16)&1u)) >> 16;
  return (ushort)r;
}
__device__ __forceinline__ void async16(const ushort* g, ushort* l){
  __builtin_amdgcn_global_load_lds(
      (const __attribute__((address_space(1))) unsigned int*)g,
      (__attribute__((address_space(3))) unsigned int*)l, 16, 0, 0);
}

struct KParams {
  const float *input_embs, *mask, *pos, *ln_emb_g, *ln_emb_b;
  const float *Wq,*bq,*Wk,*bk,*Wv,*bv,*Wo,*bo,*ln1_g,*ln1_b;
  const float *Wi,*bi,*Wo2,*bo2,*ln2_g,*ln2_b,*pW1,*pb1,*pW2,*pb2;
  ushort *WqkvT,*WoT,*WiT,*Wo2T,*pW1T;
  float *bqkv;
  ushort *h16; float *h32;
  ushort *qkv, *ctx, *attn16; float *attn32;
  ushort *inter;
  float *t1, *alpha, *invsum, *outacc, *out;
};

// ---------------------------------------------------------------- prep
__device__ void tr_tile32(char* smemc, const float* __restrict__ src,
    ushort* __restrict__ dst, int R, int C, int r0, int c0)
{
  ushort (*tile)[33] = (ushort(*)[33])smemc;
  int tx = threadIdx.x & 31, ty = threadIdx.x >> 5;
  #pragma unroll
  for (int i = 0; i < 4; ++i)
    tile[ty + i*8][tx] = f2b(src[(size_t)(r0 + ty + i*8)*C + c0 + tx]);
  __syncthreads();
  #pragma unroll
  for (int i = 0; i < 4; ++i)
    dst[(size_t)(c0 + ty + i*8)*R + r0 + tx] = tile[tx][ty + i*8];
  __syncthreads();
}

__device__ void prep_job(const KParams& p, char* smemc, int j)
{
  if (j < 4352){
    int z = j >> 8, t = j & 255;
    const float* src; ushort* dst;
    if (z < 12){
      int kind = z >> 2, l = z & 3;
      const float* s3 = (kind == 0) ? p.Wq : ((kind == 1) ? p.Wk : p.Wv);
      src = s3 + (size_t)l*512*512;
      dst = p.WqkvT + (size_t)l*1536*512 + (size_t)kind*512*512;
    } else if (z < 16){
      int l = z - 12; src = p.Wo + (size_t)l*512*512; dst = p.WoT + (size_t)l*512*512;
    } else { src = p.pW1; dst = p.pW1T; }
    tr_tile32(smemc, src, dst, 512, 512, (t >> 4)*32, (t & 15)*32);
  } else if (j < 8448){
    int j2 = j - 4352; int z = j2 >> 10, t = j2 & 1023;
    tr_tile32(smemc, p.Wi + (size_t)z*512*2048, p.WiT + (size_t)z*2048*512,
              512, 2048, (t >> 6)*32, (t & 63)*32);
  } else if (j < 12544){
    int j3 = j - 8448; int z = j3 >> 10, t = j3 & 1023;
    tr_tile32(smemc, p.Wo2 + (size_t)z*2048*512, p.Wo2T + (size_t)z*512*2048,
              2048, 512, (t >> 4)*32, (t & 15)*32);
  } else {
    int i = (j - 12544)*256 + threadIdx.x;
    int l = i / 1536, n = i % 1536;
    float v = (n < 512) ? p.bq[l*512 + n]
            : (n < 1024 ? p.bk[l*512 + n - 512] : p.bv[l*512 + n - 1024]);
    p.bqkv[i] = v;
  }
}

// ---------------------------------------------------------------- GEMM (BM=64)
__device__ void gemm64(char* smemc, const ushort* __restrict__ A,
    const ushort* __restrict__ Bt, const float* __restrict__ bias,
    ushort* __restrict__ o16, float* __restrict__ o32,
    int M, int N, int K, int Klen, int epi, int bx, int by, int bz)
{
  ushort* lds = (ushort*)smemc;
  constexpr int ABUF = 64*64;
  constexpr int BUFE = ABUF + 128*64;
  const int tid = threadIdx.x;
  const int bm = by*64, bn = bx*128;
  const int kbeg = bz * Klen;
  const int wave = tid >> 6, lane = tid & 63;
  const int wr = (wave >> 1)*32, wc = (wave & 1)*64;
  const int lr = lane & 15, lg = lane >> 4, l7 = lr & 7;
  f32x4 acc[2][4] = {};

  const ushort* srcA[2];
  const ushort* srcB[4];
  #pragma unroll
  for (int ra = 0; ra < 2; ++ra){
    int s = tid + ra*256; int r = s >> 3, g = s & 7;
    srcA[ra] = A + (size_t)(bm + r)*K + kbeg + ((g ^ (r & 7))*8);
  }
  #pragma unroll
  for (int rb = 0; rb < 4; ++rb){
    int s = tid + rb*256; int r = s >> 3, g = s & 7;
    srcB[rb] = Bt + (size_t)(bn + r)*K + kbeg + ((g ^ (r & 7))*8);
  }

  const int nIter = Klen >> 6;
  auto issueTile = [&](int t, int buf){
    int k0 = t << 6;
    ushort* dA = lds + buf*BUFE + tid*8;
    ushort* dB = lds + buf*BUFE + ABUF + tid*8;
    #pragma unroll
    for (int ra = 0; ra < 2; ++ra) async16(srcA[ra] + k0, dA + ra*2048);
    #pragma unroll
    for (int rb = 0; rb < 4; ++rb) async16(srcB[rb] + k0, dB + rb*2048);
  };

  issueTile(0, 0);
  asm volatile("s_waitcnt vmcnt(0)" ::: "memory");
  __builtin_amdgcn_s_barrier();

  int cur = 0;
  for (int t = 0; t < nIter; ++t){
    if (t + 1 < nIter) issueTile(t + 1, cur ^ 1);
    const ushort* bufp = lds + cur*BUFE;
    #pragma unroll
    for (int ks = 0; ks < 2; ++ks){
      short8v af[2], bfr[4];
      #pragma unroll
      for (int mi = 0; mi < 2; ++mi){
        int R = wr + mi*16 + lr;
        af[mi] = *(const short8v*)(bufp + R*64 + (((ks*4 + lg) ^ l7)*8));
      }
      #pragma unroll
      for (int nj = 0; nj < 4; ++nj){
        int Rb = wc + nj*16 + lr;
        bfr[nj] = *(const short8v*)(bufp + ABUF + Rb*64 + (((ks*4 + lg) ^ l7)*8));
      }
      #pragma unroll
      for (int mi = 0; mi < 2; ++mi)
        #pragma unroll
        for (int nj = 0; nj < 4; ++nj)
          acc[mi][nj] = __builtin_amdgcn_mfma_f32_16x16x32_bf16(af[mi], bfr[nj], acc[mi][nj], 0, 0, 0);
    }
    asm volatile("s_waitcnt vmcnt(0)" ::: "memory");
    __builtin_amdgcn_s_barrier();
    cur ^= 1;
  }

  const float bscale = (bz == 0) ? 1.0f : 0.0f;
  #pragma unroll
  for (int mi = 0; mi < 2; ++mi){
    #pragma unroll
    for (int nj = 0; nj < 4; ++nj){
      int col = bn + wc + nj*16 + lr;
      float bv = bias[col] * bscale;
      #pragma unroll
      for (int j = 0; j < 4; ++j){
        int row = bm + wr + mi*16 + lg*4 + j;
        float v = acc[mi][nj][j] + bv;
        if (epi == 1) v = 0.5f * v * (1.0f + erff(v * 0.70710678118654752f));
        if (epi == 2) v = tanhf(v);
        if (epi == 3) o32[(size_t)bz*M*N + (size_t)row*N + col] = v;
        else          o16[(size_t)row*N + col] = f2b(v);
      }
    }
  }
  __syncthreads();
}

// ---------------------------------------------------------------- LN rows
__device__ void ln_core(float v0, float v1, float* red, float& mean, float& rstd)
{
  int tid = threadIdx.x, wave = tid >> 6, lane = tid & 63;
  float sm = v0 + v1, sq = v0*v0 + v1*v1;
  #pragma unroll
  for (int o = 32; o > 0; o >>= 1){ sm += __shfl_xor(sm, o); sq += __shfl_xor(sq, o); }
  if (lane == 0){ red[wave] = sm; red[4 + wave] = sq; }
  __syncthreads();
  float S = red[0] + red[1] + red[2] + red[3];
  float Q = red[4] + red[5] + red[6] + red[7];
  mean = S * (1.0f/512.0f);
  float var = Q * (1.0f/512.0f) - mean*mean;
  if (var < 0.f) var = 0.f;
  rstd = rsqrtf(var + 1e-12f);
  __syncthreads();
}

__device__ void embed_row(const KParams& p, char* smemc, int row)
{
  float* red = (float*)smemc;
  int tid = threadIdx.x;
  int s = row & (S_ - 1);
  const size_t base = (size_t)row*H_ + tid*2;
  float2 xv = *(const float2*)(p.input_embs + base);
  float2 pv = *(const float2*)(p.pos + (size_t)s*H_ + tid*2);
  float v0 = xv.x + pv.x, v1 = xv.y + pv.y;
  float mean, rstd;
  ln_core(v0, v1, red, mean, rstd);
  float2 gv = *(const float2*)(p.ln_emb_g + tid*2);
  float2 bv = *(const float2*)(p.ln_emb_b + tid*2);
  float r0 = (v0 - mean)*rstd*gv.x + bv.x;
  float r1 = (v1 - mean)*rstd*gv.y + bv.y;
  ushort2 o2; o2.x = f2b(r0); o2.y = f2b(r1);
  *(ushort2*)(p.h16 + base) = o2;
  float2 f2v; f2v.x = r0; f2v.y = r1;
  *(float2*)(p.h32 + base) = f2v;
}

__device__ void lnres_row(const float* __restrict__ t, const float* __restrict__ res,
    const float* __restrict__ g, const float* __restrict__ bb,
    ushort* __restrict__ out16, float* __restrict__ out32, char* smemc, int row)
{
  float* red = (float*)smemc;
  int tid = threadIdx.x;
  const size_t MN = (size_t)M_*H_;
  const size_t base = (size_t)row*H_ + tid*2;
  float2 t0 = *(const float2*)(t + base);
  float2 t1v = *(const float2*)(t + MN + base);
  float2 rv = *(const float2*)(res + base);
  float v0 = t0.x + t1v.x + rv.x;
  float v1 = t0.y + t1v.y + rv.y;
  float mean, rstd;
  ln_core(v0, v1, red, mean, rstd);
  float2 gv = *(const float2*)(g + tid*2);
  float2 bv = *(const float2*)(bb + tid*2);
  float r0 = (v0 - mean)*rstd*gv.x + bv.x;
  float r1 = (v1 - mean)*rstd*gv.y + bv.y;
  ushort2 o2; o2.x = f2b(r0); o2.y = f2b(r1);
  *(ushort2*)(out16 + base) = o2;
  float2 f2v; f2v.x = r0; f2v.y = r1;
  *(float2*)(out32 + base) = f2v;
}

// ---------------------------------------------------------------- attention
__device__ void attn_job(const KParams& p, char* smemc, int job)
{
  ushort* K_lin = (ushort*)smemc;
  ushort (*Vt)[136]    = (ushort(*)[136])(smemc + 16384);
  ushort (*P_lds)[136] = (ushort(*)[136])(smemc + 16384 + 17408);
  float* kb = (float*)(smemc + 16384 + 17408 + 17408);

  const int tid = threadIdx.x, wave = tid >> 6, lane = tid & 63;
  const int bx = job & 31, byy = job >> 5;
  const int hh = byy & (NH_ - 1), b = byy >> 3;
  const int s0 = bx * 64;
  const size_t rb = (size_t)b * S_;
  const ushort* qkv = p.qkv;

  #pragma unroll
  for (int r = 0; r < 4; ++r){
    int s = tid + r*256;
    int row = s >> 3, g = s & 7;
    int j = s0 - 32 + row;
    int jc = min(max(j, 0), S_ - 1);
    const ushort* src = qkv + (rb + jc)*1536 + 512 + hh*64 + ((g ^ (row & 7))*8);
    async16(src, K_lin + tid*8 + r*2048);
  }
  const int ch = tid & 7, rr = tid >> 3;
  #pragma unroll
  for (int it = 0; it < 2; ++it){
    int c0 = rr*2 + it*64;
    short8v vv[2];
    #pragma unroll
    for (int pp = 0; pp < 2; ++pp){
      int c = c0 + pp;
      int j = s0 - 32 + c;
      int jc = min(max(j, 0), S_ - 1);
      vv[pp] = *(const short8v*)(qkv + (rb + jc)*1536 + 1024 + hh*64 + ch*8);
    }
    #pragma unroll
    for (int t = 0; t < 8; ++t){
      int tt = (t + ch) & 7;
      int d = ch*8 + tt;
      ushort2 w; w.x = (ushort)vv[0][tt]; w.y = (ushort)vv[1][tt];
      *(ushort2*)(&Vt[d][c0]) = w;
    }
  }
  if (tid < 128){
    int j = s0 - 32 + tid;
    kb[tid] = (j >= 0 && j < S_) ? (1.0f - p.mask[rb + j]) * (-10000.0f) : -1e30f;
  }
  __syncthreads();

  const int wq0 = wave * 16;
  const int lr = lane & 15, lg = lane >> 4, lk = lg*8, l7 = lr & 7;

  const ushort* qbase = qkv + (rb + s0 + wq0 + lr)*1536 + hh*64;
  short8v aq0 = *(const short8v*)(qbase + lk);
  short8v aq1 = *(const short8v*)(qbase + 32 + lk);

  f32x4 sacc[8];
  #pragma unroll
  for (int cn = 0; cn < 8; ++cn){
    int row = cn*16 + lr;
    short8v bk0 = *(const short8v*)(&K_lin[row*64 + ((lg ^ l7)*8)]);
    short8v bk1 = *(const short8v*)(&K_lin[row*64 + (((4 + lg) ^ l7)*8)]);
    f32x4 z = {0.f,0.f,0.f,0.f};
    z = __builtin_amdgcn_mfma_f32_16x16x32_bf16(aq0, bk0, z, 0, 0, 0);
    z = __builtin_amdgcn_mfma_f32_16x16x32_bf16(aq1, bk1, z, 0, 0, 0);
    sacc[cn] = z;
  }
  #pragma unroll
  for (int jr = 0; jr < 4; ++jr){
    const int R = wq0 + lg*4 + jr;
    float v[8], mx = -1e30f;
    #pragma unroll
    for (int cn = 0; cn < 8; ++cn){
      int c = cn*16 + lr;
      float sc = sacc[cn][jr]*0.125f + kb[c];
      if (c < R || c > R + 64) sc = -1e30f;
      v[cn] = sc;
      mx = fmaxf(mx, sc);
    }
    #pragma unroll
    for (int o = 1; o < 16; o <<= 1) mx = fmaxf(mx, __shfl_xor(mx, o));
    float sum = 0.f;
    #pragma unroll
    for (int cn = 0; cn < 8; ++cn){ v[cn] = __expf(v[cn] - mx); sum += v[cn]; }
    #pragma unroll
    for (int o = 1; o < 16; o <<= 1) sum += __shfl_xor(sum, o);
    float qm = p.mask[rb + s0 + R];
    float inv = ((qm < 0.999f) ? 0.0f : 1.0f) / sum;
    #pragma unroll
    for (int cn = 0; cn < 8; ++cn)
      P_lds[R][cn*16 + lr] = f2b(v[cn] * inv);
  }
  short8v ap[4];
  #pragma unroll
  for (int ks = 0; ks < 4; ++ks)
    ap[ks] = *(const short8v*)(&P_lds[wq0 + lr][ks*32 + lk]);
  #pragma unroll
  for (int dn = 0; dn < 4; ++dn){
    f32x4 z = {0.f,0.f,0.f,0.f};
    #pragma unroll
    for (int ks = 0; ks < 4; ++ks){
      short8v bv = *(const short8v*)(&Vt[dn*16 + lr][ks*32 + lk]);
      z = __builtin_amdgcn_mfma_f32_16x16x32_bf16(ap[ks], bv, z, 0, 0, 0);
    }
    #pragma unroll
    for (int jr = 0; jr < 4; ++jr){
      int R = wq0 + lg*4 + jr;
      p.ctx[(rb + s0 + R)*H_ + hh*64 + dn*16 + lr] = f2b(z[jr]);
    }
  }
  __syncthreads();
}

// ---------------------------------------------------------------- pooling
__device__ void plogit_job(const KParams& p, int job)
{
  int tid = threadIdx.x, wave = tid >> 6, lane = tid & 63;
  int r = job*4 + wave;
  short8v ev = *(const short8v*)(p.ctx + (size_t)r*H_ + lane*8);
  float sacc = 0.f;
  #pragma unroll
  for (int j = 0; j < 8; ++j) sacc += b2f((ushort)ev[j]) * p.pW2[lane*8 + j];
  #pragma unroll
  for (int o = 32; o > 0; o >>= 1) sacc += __shfl_xor(sacc, o);
  if (lane == 0){
    float logit = sacc + p.pb2[0];
    p.alpha[r] = __expf(logit) * p.mask[r];
  }
}

__device__ void psum_job(const KParams& p, char* smemc, int b)
{
  float* red = (float*)smemc;
  int tid = threadIdx.x, wave = tid >> 6, lane = tid & 63;
  float s = 0.f;
  for (int k = tid; k < S_; k += 256) s += p.alpha[b*S_ + k];
  #pragma unroll
  for (int o = 32; o > 0; o >>= 1) s += __shfl_xor(s, o);
  if (lane == 0) red[wave] = s;
  __syncthreads();
  if (tid == 0) p.invsum[b] = 1.0f / (red[0] + red[1] + red[2] + red[3] + 1e-8f);
  __syncthreads();
}

__device__ void pwsum_job(const KParams& p, int job)
{
  int chunk = job & 15, b = job >> 4, tid = threadIdx.x;
  int s0 = chunk * 128, c0 = tid * 2;
  float a0 = 0.f, a1 = 0.f;
  for (int i = 0; i < 128; ++i){
    int srow = s0 + i;
    float al = p.alpha[b*S_ + srow];
    float2 xv = *(const float2*)(p.h32 + (size_t)(b*S_ + srow)*H_ + c0);
    a0 += xv.x * al;
    a1 += xv.y * al;
  }
  float2 o; o.x = a0; o.y = a1;
  *(float2*)(p.outacc + (size_t)chunk*B_*H_ + b*H_ + c0) = o;
}

__device__ void pfinal_job(const KParams& p, int job)
{
  int i = job*256 + threadIdx.x;
  if (i < B_*H_){
    int b = i >> 9;
    float s = 0.f;
    #pragma unroll
    for (int c = 0; c < 16; ++c) s += p.outacc[(size_t)c*B_*H_ + i];
    p.out[i] = s * p.invsum[b];
  }
}

// ---------------------------------------------------------------- fused (cooperative)
__global__ __launch_bounds__(256, 2) void fused_all(KParams p, int nb)
{
  __shared__ __align__(16) char smem[51712];
  cg::grid_group grid = cg::this_grid();
  const int bid = blockIdx.x;

  for (int j = bid; j < 12568; j += nb) prep_job(p, smem, j);
  grid.sync();
  for (int j = bid; j < M_; j += nb) embed_row(p, smem, j);
  grid.sync();

  for (int l = 0; l < L_; ++l){
    const ushort* WqkvTl = p.WqkvT + (size_t)l*1536*512;
    for (int j = bid; j < 768; j += nb)
      gemm64(smem, p.h16, WqkvTl, p.bqkv + l*1536, p.qkv, nullptr,
             M_, 1536, 512, 512, 0, j % 12, j / 12, 0);
    grid.sync();
    for (int j = bid; j < 512; j += nb) attn_job(p, smem, j);
    grid.sync();
    for (int j = bid; j < 512; j += nb)
      gemm64(smem, p.ctx, p.WoT + (size_t)l*512*512, p.bo + l*512, nullptr, p.t1,
             M_, 512, 512, 256, 3, j & 3, (j >> 2) & 63, j >> 8);
    grid.sync();
    for (int j = bid; j < M_; j += nb)
      lnres_row(p.t1, p.h32, p.ln1_g + l*512, p.ln1_b + l*512, p.attn16, p.attn32, smem, j);
    grid.sync();
    for (int j = bid; j < 1024; j += nb)
      gemm64(smem, p.attn16, p.WiT + (size_t)l*2048*512, p.bi + l*2048, p.inter, nullptr,
             M_, 2048, 512, 512, 1, j & 15, j >> 4, 0);
    grid.sync();
    for (int j = bid; j < 512; j += nb)
      gemm64(smem, p.inter, p.Wo2T + (size_t)l*512*2048, p.bo2 + l*512, nullptr, p.t1,
             M_, 512, 2048, 1024, 3, j & 3, (j >> 2) & 63, j >> 8);
    grid.sync();
    for (int j = bid; j < M_; j += nb)
      lnres_row(p.t1, p.attn32, p.ln2_g + l*512, p.ln2_b + l*512, p.h16, p.h32, smem, j);
    grid.sync();
  }

  for (int j = bid; j < 256; j += nb)
    gemm64(smem, p.h16, p.pW1T, p.pb1, p.ctx, nullptr, M_, 512, 512, 512, 2, j & 3, j >> 2, 0);
  grid.sync();
  for (int j = bid; j < 1024; j += nb) plogit_job(p, j);
  grid.sync();
  for (int j = bid; j < 34; j += nb){
    if (j < 2) psum_job(p, smem, j);
    else       pwsum_job(p, j - 2);
  }
  grid.sync();
  for (int j = bid; j < 4; j += nb) pfinal_job(p, j);
}

// ---------------------------------------------------------------- fallback wrappers
__global__ __launch_bounds__(256) void prep_k(KParams p){
  __shared__ __align__(16) char smem[2560];
  prep_job(p, smem, blockIdx.x);
}
__global__ __launch_bounds__(256) void embed_k(KParams p){
  __shared__ __align__(16) char smem[64];
  embed_row(p, smem, blockIdx.x);
}
__global__ __launch_bounds__(256, 3) void gemm_k(const ushort* A, const ushort* Bt,
    const float* bias, ushort* o16, float* o32, int M, int N, int K, int Klen, int epi){
  __shared__ __align__(16) char smem[49152];
  gemm64(smem, A, Bt, bias, o16, o32, M, N, K, Klen, epi,
         blockIdx.x, blockIdx.y, blockIdx.z);
}
__global__ __launch_bounds__(256) void attn_k(KParams p){
  __shared__ __align__(16) char smem[51712];
  attn_job(p, smem, blockIdx.x);
}
__global__ __launch_bounds__(256) void lnres_k(const float* t, const float* res,
    const float* g, const float* bb, ushort* o16, float* o32){
  __shared__ __align__(16) char smem[64];
  lnres_row(t, res, g, bb, o16, o32, smem, blockIdx.x);
}
__global__ __launch_bounds__(256) void plogit_k(KParams p){ plogit_job(p, blockIdx.x); }
__global__ __launch_bounds__(256) void psum_k(KParams p){
  __shared__ __align__(16) char smem[64];
  psum_job(p, smem, blockIdx.x);
}
__global__ __launch_bounds__(256) void pwsum_k(KParams p){ pwsum_job(p, blockIdx.x); }
__global__ __launch_bounds__(256) void pfinal_k(KParams p){ pfinal_job(p, blockIdx.x); }

// ---------------------------------------------------------------- launch
extern "C" void kernel_launch(void* const* d_in, const int* in_sizes, int n_in,
                              void* d_out, int out_size, void* d_ws, size_t ws_size,
                              hipStream_t stream)
{
  KParams p;
  p.input_embs = (const float*)d_in[0];
  p.mask       = (const float*)d_in[1];
  p.pos        = (const float*)d_in[2];
  p.ln_emb_g   = (const float*)d_in[3];
  p.ln_emb_b   = (const float*)d_in[4];
  p.Wq  = (const float*)d_in[5];   p.bq  = (const float*)d_in[6];
  p.Wk  = (const float*)d_in[7];   p.bk  = (const float*)d_in[8];
  p.Wv  = (const float*)d_in[9];   p.bv  = (const float*)d_in[10];
  p.Wo  = (const float*)d_in[11];  p.bo  = (const float*)d_in[12];
  p.ln1_g = (const float*)d_in[13]; p.ln1_b = (const float*)d_in[14];
  p.Wi  = (const float*)d_in[15];  p.bi  = (const float*)d_in[16];
  p.Wo2 = (const float*)d_in[17];  p.bo2 = (const float*)d_in[18];
  p.ln2_g = (const float*)d_in[19]; p.ln2_b = (const float*)d_in[20];
  p.pW1 = (const float*)d_in[21];  p.pb1 = (const float*)d_in[22];
  p.pW2 = (const float*)d_in[23];  p.pb2 = (const float*)d_in[24];

  char* ws = (char*)d_ws;
  size_t off = 0;
  auto alloc = [&](size_t bytes)->char*{
    char* q = ws + off; off += (bytes + 255) & ~(size_t)255; return q;
  };
  p.WqkvT  = (ushort*)alloc((size_t)L_*1536*512*2);
  p.WoT    = (ushort*)alloc((size_t)L_*512*512*2);
  p.WiT    = (ushort*)alloc((size_t)L_*2048*512*2);
  p.Wo2T   = (ushort*)alloc((size_t)L_*512*2048*2);
  p.pW1T   = (ushort*)alloc((size_t)512*512*2);
  p.bqkv   = (float*)alloc((size_t)L_*1536*4);
  p.h16    = (ushort*)alloc((size_t)M_*H_*2);
  p.h32    = (float*)alloc((size_t)M_*H_*4);
  p.qkv    = (ushort*)alloc((size_t)M_*1536*2);
  p.ctx    = (ushort*)alloc((size_t)M_*H_*2);
  p.attn16 = (ushort*)alloc((size_t)M_*H_*2);
  p.attn32 = (float*)alloc((size_t)M_*H_*4);
  p.inter  = (ushort*)alloc((size_t)M_*INTER_*2);
  p.t1     = (float*)alloc((size_t)2*M_*H_*4);
  p.alpha  = (float*)alloc((size_t)M_*4);
  p.invsum = (float*)alloc(256);
  p.outacc = (float*)alloc((size_t)16*B_*H_*4);
  p.out    = (float*)d_out;

  // ---- try persistent cooperative kernel; fall back to dispatch sequence
  hipError_t err = hipErrorUnknown;
  int dev = 0, coop = 0, maxb = 0;
  hipGetDevice(&dev);
  hipDeviceGetAttribute(&coop, hipDeviceAttributeCooperativeLaunch, dev);
  if (coop){
    hipError_t oq = hipOccupancyMaxActiveBlocksPerMultiprocessor(
        &maxb, (const void*)fused_all, 256, 0);
    if (oq == hipSuccess && maxb > 0){
      int nb = maxb * 256;           // 256 CUs
      if (nb > 512) nb = 512;
      void* args[] = { &p, &nb };
      err = hipLaunchCooperativeKernel((const void*)fused_all, dim3(nb), dim3(256),
                                       args, 0, stream);
    }
  }
  if (err != hipSuccess){
    dim3 tb(256);
    prep_k<<<dim3(12568), tb, 0, stream>>>(p);
    embed_k<<<dim3(M_), tb, 0, stream>>>(p);
    for (int l = 0; l < L_; ++l){
      gemm_k<<<dim3(12,64,1), tb, 0, stream>>>(p.h16, p.WqkvT + (size_t)l*1536*512,
          p.bqkv + l*1536, p.qkv, nullptr, M_, 1536, 512, 512, 0);
      attn_k<<<dim3(512), tb, 0, stream>>>(p);
      gemm_k<<<dim3(4,64,2), tb, 0, stream>>>(p.ctx, p.WoT + (size_t)l*512*512,
          p.bo + l*512, nullptr, p.t1, M_, 512, 512, 256, 3);
      lnres_k<<<dim3(M_), tb, 0, stream>>>(p.t1, p.h32, p.ln1_g + l*512, p.ln1_b + l*512,
          p.attn16, p.attn32);
      gemm_k<<<dim3(16,64,1), tb, 0, stream>>>(p.attn16, p.WiT + (size_t)l*2048*512,
          p.bi + l*2048, p.inter, nullptr, M_, 2048, 512, 512, 1);
      gemm_k<<<dim3(4,64,2), tb, 0, stream>>>(p.inter, p.Wo2T + (size_t)l*512*2048,
          p.bo2 + l*512, nullptr, p.t1, M_, 512, 2048, 1024, 3);
      lnres_k<<<dim3(M_), tb, 0, stream>>>(p.t1, p.attn32, p.ln2_g + l*512, p.ln2_b + l*512,
          p.h16, p.h32);
    }
    gemm_k<<<dim3(4,64,1), tb, 0, stream>>>(p.h16, p.pW1T, p.pb1, p.ctx, nullptr,
        M_, 512, 512, 512, 2);
    plogit_k<<<dim3(1024), tb, 0, stream>>>(p);
    psum_k<<<dim3(2), tb, 0, stream>>>(p);
    pwsum_k<<<dim3(32), tb, 0, stream>>>(p);
    pfinal_k<<<dim3(4), tb, 0, stream>>>(p);
  }
}

// Round 16
// 401.709 us; speedup vs baseline: 4.0909x; 4.0909x over previous
//
#include <hip/hip_runtime.h>
#include <hip/hip_bf16.h>
#include <math.h>

#define B_ 2
#define S_ 2048
#define H_ 512
#define NH_ 8
#define HD_ 64
#define L_ 4
#define INTER_ 2048
#define W1_ 32
#define M_ (B_*S_)   // 4096

typedef __attribute__((ext_vector_type(8))) short short8v;
typedef __attribute__((ext_vector_type(4))) float f32x4;

__device__ __forceinline__ float b2f(ushort u){ return __uint_as_float(((unsigned)u)<<16); }
__device__ __forceinline__ ushort f2b(float f){
  unsigned u = __float_as_uint(f);
  unsigned r = (u + 0x7fffu + ((u>>16)&1u)) >> 16;
  return (ushort)r;
}
__device__ __forceinline__ void async16(const ushort* g, ushort* l){
  __builtin_amdgcn_global_load_lds(
      (const __attribute__((address_space(1))) unsigned int*)g,
      (__attribute__((address_space(3))) unsigned int*)l, 16, 0, 0);
}

// ---------------------------------------------------------------- transposes
__device__ __forceinline__ void tr_tile(const float* __restrict__ src,
    ushort* __restrict__ dst, int R, int C, int r0, int c0)
{
  __shared__ ushort tile[32][33];
  int tx = threadIdx.x & 31, ty = threadIdx.x >> 5;
  #pragma unroll
  for (int i = 0; i < 4; ++i)
    tile[ty + i*8][tx] = f2b(src[(size_t)(r0 + ty + i*8)*C + c0 + tx]);
  __syncthreads();
  #pragma unroll
  for (int i = 0; i < 4; ++i)
    dst[(size_t)(c0 + ty + i*8)*R + r0 + tx] = tile[tx][ty + i*8];
}

struct TPack {
  const float* wq; const float* wk; const float* wv;
  const float* wo; const float* pw1;
  ushort* wqkvT; ushort* woT; ushort* pw1T;
};

__global__ __launch_bounds__(256) void transpose512_all(TPack p)
{
  int z = blockIdx.z;
  const float* src; ushort* dst;
  if (z < 12){
    int kind = z >> 2, l = z & 3;
    const float* s3[3] = {p.wq, p.wk, p.wv};
    src = s3[kind] + (size_t)l*512*512;
    dst = p.wqkvT + (size_t)l*1536*512 + (size_t)kind*512*512;
  } else if (z < 16){
    int l = z - 12;
    src = p.wo + (size_t)l*512*512;
    dst = p.woT + (size_t)l*512*512;
  } else {
    src = p.pw1; dst = p.pw1T;
  }
  tr_tile(src, dst, 512, 512, blockIdx.y*32, blockIdx.x*32);
}

__global__ __launch_bounds__(256) void transpose_k(const float* __restrict__ src,
    ushort* __restrict__ dst, int R, int C, size_t sBatch, size_t dBatch)
{
  src += (size_t)blockIdx.z * sBatch;
  dst += (size_t)blockIdx.z * dBatch;
  tr_tile(src, dst, R, C, blockIdx.y*32, blockIdx.x*32);
}

__global__ __launch_bounds__(256) void pack_bqkv(const float* __restrict__ bq,
    const float* __restrict__ bk, const float* __restrict__ bv, float* __restrict__ dst)
{
  int i = blockIdx.x * 256 + threadIdx.x;
  int l = i / 1536, n = i % 1536;
  float v = (n < 512) ? bq[l*512 + n] : (n < 1024 ? bk[l*512 + n - 512] : bv[l*512 + n - 1024]);
  dst[i] = v;
}

// ---------------------------------------------------------------- GEMM (B^T)
// BM x 128 tile, BK=64; 4 waves; 2-buffer issue-early pipeline, ONE barrier
// per K-step; XOR-swizzled LDS (granule ^ (row&7), both sides).
// HARD CONSTRAINT (R6/R12): N=512 GEMMs need >=2 blocks/CU -> keep split-K z=2.
// HARD CONSTRAINT (R15): no cooperative/persistent kernels (grid.sync ~36us).
template<int EPI, int BM>
__global__ __launch_bounds__(256, (BM == 64) ? 3 : 2) void gemm_bt(
    const ushort* __restrict__ A, const ushort* __restrict__ Bt,
    const float* __restrict__ bias, ushort* __restrict__ o16,
    float* __restrict__ o32, int M, int N, int K, int Klen)
{
  constexpr int ABUF = BM * 64;
  constexpr int BUFE = ABUF + 128 * 64;
  constexpr int MI = BM / 32;
  constexpr int AR = (BM * 8) / 256;
  constexpr int BR = 4;
  __shared__ ushort lds[2 * BUFE];
  const int tid = threadIdx.x;
  const int bm = blockIdx.y * BM, bn = blockIdx.x * 128;
  const int kbeg = blockIdx.z * Klen;
  const int wave = tid >> 6, lane = tid & 63;
  const int wr = (wave >> 1) * (BM / 2), wc = (wave & 1) * 64;
  const int lr = lane & 15, lg = lane >> 4;
  const int l7 = lr & 7;
  f32x4 acc[MI][4] = {};

  const ushort* srcA[AR];
  const ushort* srcB[BR];
  #pragma unroll
  for (int ra = 0; ra < AR; ++ra){
    int s = tid + ra*256; int r = s >> 3, g = s & 7;
    srcA[ra] = A + (size_t)(bm + r) * K + kbeg + ((g ^ (r & 7)) * 8);
  }
  #pragma unroll
  for (int rb = 0; rb < BR; ++rb){
    int s = tid + rb*256; int r = s >> 3, g = s & 7;
    srcB[rb] = Bt + (size_t)(bn + r) * K + kbeg + ((g ^ (r & 7)) * 8);
  }

  const int nIter = Klen >> 6;
  auto issueTile = [&](int t, int buf){
    int k0 = t << 6;
    ushort* dA = &lds[0] + buf*BUFE + tid*8;
    ushort* dB = &lds[0] + buf*BUFE + ABUF + tid*8;
    #pragma unroll
    for (int ra = 0; ra < AR; ++ra) async16(srcA[ra] + k0, dA + ra*2048);
    #pragma unroll
    for (int rb = 0; rb < BR; ++rb) async16(srcB[rb] + k0, dB + rb*2048);
  };

  issueTile(0, 0);
  asm volatile("s_waitcnt vmcnt(0)" ::: "memory");
  __builtin_amdgcn_s_barrier();

  int cur = 0;
  for (int t = 0; t < nIter; ++t){
    if (t + 1 < nIter) issueTile(t + 1, cur ^ 1);
    const ushort* bufp = &lds[0] + cur*BUFE;
    #pragma unroll
    for (int ks = 0; ks < 2; ++ks){
      short8v af[MI], bfr[4];
      #pragma unroll
      for (int mi = 0; mi < MI; ++mi){
        int R = wr + mi*16 + lr;
        af[mi] = *(const short8v*)(bufp + R*64 + (((ks*4 + lg) ^ l7) * 8));
      }
      #pragma unroll
      for (int nj = 0; nj < 4; ++nj){
        int Rb = wc + nj*16 + lr;
        bfr[nj] = *(const short8v*)(bufp + ABUF + Rb*64 + (((ks*4 + lg) ^ l7) * 8));
      }
      #pragma unroll
      for (int mi = 0; mi < MI; ++mi)
        #pragma unroll
        for (int nj = 0; nj < 4; ++nj)
          acc[mi][nj] = __builtin_amdgcn_mfma_f32_16x16x32_bf16(af[mi], bfr[nj], acc[mi][nj], 0, 0, 0);
    }
    asm volatile("s_waitcnt vmcnt(0)" ::: "memory");
    __builtin_amdgcn_s_barrier();
    cur ^= 1;
  }

  const float bscale = (blockIdx.z == 0) ? 1.0f : 0.0f;
  #pragma unroll
  for (int mi = 0; mi < MI; ++mi){
    #pragma unroll
    for (int nj = 0; nj < 4; ++nj){
      int col = bn + wc + nj*16 + lr;
      float bv = bias[col] * bscale;
      #pragma unroll
      for (int j = 0; j < 4; ++j){
        int row = bm + wr + mi*16 + lg*4 + j;
        float v = acc[mi][nj][j] + bv;
        if (EPI == 1) v = 0.5f * v * (1.0f + erff(v * 0.70710678118654752f));
        if (EPI == 2) v = tanhf(v);
        if (EPI == 3) o32[(size_t)blockIdx.z*M*N + (size_t)row * N + col] = v;
        else          o16[(size_t)row * N + col] = f2b(v);
      }
    }
  }
}

// ---------------------------------------------------------------- LayerNorm (2 rows/block)
// one barrier for both rows: red[0..7]=row0 {sm,sq}, red[8..15]=row1
__device__ __forceinline__ void ln_stats2(float a0, float a1, float b0, float b1,
    float* red, float& meanA, float& rstdA, float& meanB, float& rstdB)
{
  int tid = threadIdx.x, wave = tid >> 6, lane = tid & 63;
  float smA = a0 + a1, sqA = a0*a0 + a1*a1;
  float smB = b0 + b1, sqB = b0*b0 + b1*b1;
  #pragma unroll
  for (int o = 32; o > 0; o >>= 1){
    smA += __shfl_xor(smA, o); sqA += __shfl_xor(sqA, o);
    smB += __shfl_xor(smB, o); sqB += __shfl_xor(sqB, o);
  }
  if (lane == 0){
    red[wave] = smA; red[4 + wave] = sqA;
    red[8 + wave] = smB; red[12 + wave] = sqB;
  }
  __syncthreads();
  float SA = red[0]+red[1]+red[2]+red[3], QA = red[4]+red[5]+red[6]+red[7];
  float SB = red[8]+red[9]+red[10]+red[11], QB = red[12]+red[13]+red[14]+red[15];
  meanA = SA * (1.0f/512.0f);
  float vA = QA * (1.0f/512.0f) - meanA*meanA; if (vA < 0.f) vA = 0.f;
  rstdA = rsqrtf(vA + 1e-12f);
  meanB = SB * (1.0f/512.0f);
  float vB = QB * (1.0f/512.0f) - meanB*meanB; if (vB < 0.f) vB = 0.f;
  rstdB = rsqrtf(vB + 1e-12f);
}

__global__ __launch_bounds__(256) void embed_ln(const float* __restrict__ x,
    const float* __restrict__ pos, const float* __restrict__ g,
    const float* __restrict__ bb, ushort* __restrict__ out16, float* __restrict__ out32)
{
  __shared__ float red[16];
  int rowA = blockIdx.x*2, rowB = rowA + 1, tid = threadIdx.x;
  int sA = rowA & (S_ - 1), sB = rowB & (S_ - 1);
  const size_t baseA = (size_t)rowA*H_ + tid*2;
  const size_t baseB = (size_t)rowB*H_ + tid*2;
  float2 xA = *(const float2*)(x + baseA);
  float2 pA = *(const float2*)(pos + (size_t)sA*H_ + tid*2);
  float2 xB = *(const float2*)(x + baseB);
  float2 pB = *(const float2*)(pos + (size_t)sB*H_ + tid*2);
  float a0 = xA.x + pA.x, a1 = xA.y + pA.y;
  float b0 = xB.x + pB.x, b1 = xB.y + pB.y;
  float mA, rA, mB, rB;
  ln_stats2(a0, a1, b0, b1, red, mA, rA, mB, rB);
  float2 gv = *(const float2*)(g + tid*2);
  float2 bv = *(const float2*)(bb + tid*2);
  float ra0 = (a0 - mA)*rA*gv.x + bv.x, ra1 = (a1 - mA)*rA*gv.y + bv.y;
  float rb0 = (b0 - mB)*rB*gv.x + bv.x, rb1 = (b1 - mB)*rB*gv.y + bv.y;
  ushort2 oA; oA.x = f2b(ra0); oA.y = f2b(ra1);
  ushort2 oB; oB.x = f2b(rb0); oB.y = f2b(rb1);
  *(ushort2*)(out16 + baseA) = oA;
  *(ushort2*)(out16 + baseB) = oB;
  float2 fA; fA.x = ra0; fA.y = ra1;
  float2 fB; fB.x = rb0; fB.y = rb1;
  *(float2*)(out32 + baseA) = fA;
  *(float2*)(out32 + baseB) = fB;
}

// LN(t0 + t1 + res32), 2 rows/block
__global__ __launch_bounds__(256) void ln_res(const float* __restrict__ t,
    const float* __restrict__ res, const float* __restrict__ g,
    const float* __restrict__ bb, ushort* __restrict__ out16, float* __restrict__ out32)
{
  __shared__ float red[16];
  int rowA = blockIdx.x*2, rowB = rowA + 1, tid = threadIdx.x;
  const size_t MN = (size_t)M_*H_;
  const size_t baseA = (size_t)rowA*H_ + tid*2;
  const size_t baseB = (size_t)rowB*H_ + tid*2;
  float2 tA0 = *(const float2*)(t + baseA);
  float2 tA1 = *(const float2*)(t + MN + baseA);
  float2 rAv = *(const float2*)(res + baseA);
  float2 tB0 = *(const float2*)(t + baseB);
  float2 tB1 = *(const float2*)(t + MN + baseB);
  float2 rBv = *(const float2*)(res + baseB);
  float a0 = tA0.x + tA1.x + rAv.x, a1 = tA0.y + tA1.y + rAv.y;
  float b0 = tB0.x + tB1.x + rBv.x, b1 = tB0.y + tB1.y + rBv.y;
  float mA, rA, mB, rB;
  ln_stats2(a0, a1, b0, b1, red, mA, rA, mB, rB);
  float2 gv = *(const float2*)(g + tid*2);
  float2 bv = *(const float2*)(bb + tid*2);
  float ra0 = (a0 - mA)*rA*gv.x + bv.x, ra1 = (a1 - mA)*rA*gv.y + bv.y;
  float rb0 = (b0 - mB)*rB*gv.x + bv.x, rb1 = (b1 - mB)*rB*gv.y + bv.y;
  ushort2 oA; oA.x = f2b(ra0); oA.y = f2b(ra1);
  ushort2 oB; oB.x = f2b(rb0); oB.y = f2b(rb1);
  *(ushort2*)(out16 + baseA) = oA;
  *(ushort2*)(out16 + baseB) = oB;
  float2 fA; fA.x = ra0; fA.y = ra1;
  float2 fB; fB.x = rb0; fB.y = rb1;
  *(float2*)(out32 + baseA) = fA;
  *(float2*)(out32 + baseB) = fB;
}

// ---------------------------------------------------------------- attention (MFMA)
__global__ __launch_bounds__(256) void attn_mfma(const ushort* __restrict__ qkv,
    const float* __restrict__ mask, ushort* __restrict__ ctx)
{
  __shared__ ushort K_lin[128*64];
  __shared__ ushort Vt[64][136];
  __shared__ ushort P_lds[64][136];
  __shared__ float  kb[128];

  const int tid = threadIdx.x, wave = tid >> 6, lane = tid & 63;
  const int hh = blockIdx.y & (NH_ - 1), b = blockIdx.y >> 3;
  const int s0 = blockIdx.x * 64;
  const size_t rb = (size_t)b * S_;

  #pragma unroll
  for (int r = 0; r < 4; ++r){
    int s = tid + r*256;
    int row = s >> 3, g = s & 7;
    int j = s0 - 32 + row;
    int jc = min(max(j, 0), S_ - 1);
    const ushort* src = qkv + (rb + jc)*1536 + 512 + hh*64 + ((g ^ (row & 7)) * 8);
    async16(src, &K_lin[0] + tid*8 + r*2048);
  }
  const int ch = tid & 7, rr = tid >> 3;
  #pragma unroll
  for (int it = 0; it < 2; ++it){
    int c0 = rr*2 + it*64;
    short8v vv[2];
    #pragma unroll
    for (int p = 0; p < 2; ++p){
      int c = c0 + p;
      int j = s0 - 32 + c;
      int jc = min(max(j, 0), S_ - 1);
      vv[p] = *(const short8v*)(qkv + (rb + jc)*1536 + 1024 + hh*64 + ch*8);
    }
    #pragma unroll
    for (int t = 0; t < 8; ++t){
      int tt = (t + ch) & 7;
      int d = ch*8 + tt;
      ushort2 w; w.x = (ushort)vv[0][tt]; w.y = (ushort)vv[1][tt];
      *(ushort2*)(&Vt[d][c0]) = w;
    }
  }
  if (tid < 128){
    int j = s0 - 32 + tid;
    kb[tid] = (j >= 0 && j < S_) ? (1.0f - mask[rb + j]) * (-10000.0f) : -1e30f;
  }
  __syncthreads();

  const int wq0 = wave * 16;
  const int lr = lane & 15, lg = lane >> 4, lk = lg * 8;
  const int l7 = lr & 7;

  const ushort* qbase = qkv + (rb + s0 + wq0 + lr) * 1536 + hh*64;
  short8v aq0 = *(const short8v*)(qbase + lk);
  short8v aq1 = *(const short8v*)(qbase + 32 + lk);

  f32x4 sacc[8];
  #pragma unroll
  for (int cn = 0; cn < 8; ++cn){
    int row = cn*16 + lr;
    short8v bk0 = *(const short8v*)(&K_lin[row*64 + ((lg ^ l7) * 8)]);
    short8v bk1 = *(const short8v*)(&K_lin[row*64 + (((4 + lg) ^ l7) * 8)]);
    f32x4 z = {0.f, 0.f, 0.f, 0.f};
    z = __builtin_amdgcn_mfma_f32_16x16x32_bf16(aq0, bk0, z, 0, 0, 0);
    z = __builtin_amdgcn_mfma_f32_16x16x32_bf16(aq1, bk1, z, 0, 0, 0);
    sacc[cn] = z;
  }
  #pragma unroll
  for (int jr = 0; jr < 4; ++jr){
    const int R = wq0 + lg*4 + jr;
    float v[8], mx = -1e30f;
    #pragma unroll
    for (int cn = 0; cn < 8; ++cn){
      int c = cn*16 + lr;
      float sc = sacc[cn][jr] * 0.125f + kb[c];
      if (c < R || c > R + 64) sc = -1e30f;
      v[cn] = sc;
      mx = fmaxf(mx, sc);
    }
    #pragma unroll
    for (int o = 1; o < 16; o <<= 1) mx = fmaxf(mx, __shfl_xor(mx, o));
    float sum = 0.f;
    #pragma unroll
    for (int cn = 0; cn < 8; ++cn){ v[cn] = __expf(v[cn] - mx); sum += v[cn]; }
    #pragma unroll
    for (int o = 1; o < 16; o <<= 1) sum += __shfl_xor(sum, o);
    float qm = mask[rb + s0 + R];
    float inv = ((qm < 0.999f) ? 0.0f : 1.0f) / sum;
    #pragma unroll
    for (int cn = 0; cn < 8; ++cn)
      P_lds[R][cn*16 + lr] = f2b(v[cn] * inv);
  }
  short8v ap[4];
  #pragma unroll
  for (int ks = 0; ks < 4; ++ks)
    ap[ks] = *(const short8v*)(&P_lds[wq0 + lr][ks*32 + lk]);
  #pragma unroll
  for (int dn = 0; dn < 4; ++dn){
    f32x4 z = {0.f, 0.f, 0.f, 0.f};
    #pragma unroll
    for (int ks = 0; ks < 4; ++ks){
      short8v bv = *(const short8v*)(&Vt[dn*16 + lr][ks*32 + lk]);
      z = __builtin_amdgcn_mfma_f32_16x16x32_bf16(ap[ks], bv, z, 0, 0, 0);
    }
    #pragma unroll
    for (int jr = 0; jr < 4; ++jr){
      int R = wq0 + lg*4 + jr;
      ctx[(rb + s0 + R)*H_ + hh*64 + dn*16 + lr] = f2b(z[jr]);
    }
  }
}

// ---------------------------------------------------------------- pooling
__global__ __launch_bounds__(256) void pool_logit(const ushort* __restrict__ e,
    const float* __restrict__ w2, const float* __restrict__ b2p,
    const float* __restrict__ mask, float* __restrict__ alpha)
{
  int tid = threadIdx.x, wave = tid >> 6, lane = tid & 63;
  int r = blockIdx.x * 4 + wave;
  short8v ev = *(const short8v*)(e + (size_t)r*H_ + lane*8);
  float sacc = 0.f;
  #pragma unroll
  for (int j = 0; j < 8; ++j) sacc += b2f((ushort)ev[j]) * w2[lane*8 + j];
  #pragma unroll
  for (int o = 32; o > 0; o >>= 1) sacc += __shfl_xor(sacc, o);
  if (lane == 0){
    float logit = sacc + b2p[0];
    alpha[r] = __expf(logit) * mask[r];
  }
}

__global__ __launch_bounds__(256) void pool_sum(const float* __restrict__ alpha,
                                                float* __restrict__ invsum)
{
  __shared__ float red[4];
  int b = blockIdx.x, tid = threadIdx.x, wave = tid >> 6, lane = tid & 63;
  float s = 0.f;
  for (int k = tid; k < S_; k += 256) s += alpha[b*S_ + k];
  #pragma unroll
  for (int o = 32; o > 0; o >>= 1) s += __shfl_xor(s, o);
  if (lane == 0) red[wave] = s;
  __syncthreads();
  if (tid == 0) invsum[b] = 1.0f / (red[0] + red[1] + red[2] + red[3] + 1e-8f);
}

__global__ __launch_bounds__(256) void pool_wsum(const float* __restrict__ x,
    const float* __restrict__ alpha, float* __restrict__ out_acc)
{
  int chunk = blockIdx.x, b = blockIdx.y, tid = threadIdx.x;
  int s0 = chunk * 128;
  int c0 = tid * 2;
  float a0 = 0.f, a1 = 0.f;
  for (int i = 0; i < 128; ++i){
    int srow = s0 + i;
    float al = alpha[b*S_ + srow];
    float2 xv = *(const float2*)(x + (size_t)(b*S_ + srow)*H_ + c0);
    a0 += xv.x * al;
    a1 += xv.y * al;
  }
  float2 o; o.x = a0; o.y = a1;
  *(float2*)(out_acc + (size_t)chunk*B_*H_ + b*H_ + c0) = o;
}

__global__ __launch_bounds__(256) void pool_final(const float* __restrict__ out_acc,
    const float* __restrict__ invsum, float* __restrict__ out)
{
  int i = blockIdx.x * 256 + threadIdx.x;
  if (i < B_*H_){
    int b = i >> 9;
    float s = 0.f;
    #pragma unroll
    for (int c = 0; c < 16; ++c) s += out_acc[(size_t)c*B_*H_ + i];
    out[i] = s * invsum[b];
  }
}

// ---------------------------------------------------------------- launch
extern "C" void kernel_launch(void* const* d_in, const int* in_sizes, int n_in,
                              void* d_out, int out_size, void* d_ws, size_t ws_size,
                              hipStream_t stream)
{
  const float* input_embs = (const float*)d_in[0];
  const float* mask       = (const float*)d_in[1];
  const float* pos        = (const float*)d_in[2];
  const float* ln_emb_g   = (const float*)d_in[3];
  const float* ln_emb_b   = (const float*)d_in[4];
  const float* Wq  = (const float*)d_in[5];
  const float* bq  = (const float*)d_in[6];
  const float* Wk  = (const float*)d_in[7];
  const float* bk  = (const float*)d_in[8];
  const float* Wv  = (const float*)d_in[9];
  const float* bv  = (const float*)d_in[10];
  const float* Wo  = (const float*)d_in[11];
  const float* bo  = (const float*)d_in[12];
  const float* ln1_g = (const float*)d_in[13];
  const float* ln1_b = (const float*)d_in[14];
  const float* Wi  = (const float*)d_in[15];
  const float* bi  = (const float*)d_in[16];
  const float* Wo2 = (const float*)d_in[17];
  const float* bo2 = (const float*)d_in[18];
  const float* ln2_g = (const float*)d_in[19];
  const float* ln2_b = (const float*)d_in[20];
  const float* pW1 = (const float*)d_in[21];
  const float* pb1 = (const float*)d_in[22];
  const float* pW2 = (const float*)d_in[23];
  const float* pb2 = (const float*)d_in[24];

  char* ws = (char*)d_ws;
  size_t off = 0;
  auto alloc = [&](size_t bytes)->char*{
    char* p = ws + off; off += (bytes + 255) & ~(size_t)255; return p;
  };
  ushort* WqkvT  = (ushort*)alloc((size_t)L_*1536*512*2);
  ushort* WoT    = (ushort*)alloc((size_t)L_*512*512*2);
  ushort* WiT    = (ushort*)alloc((size_t)L_*2048*512*2);
  ushort* Wo2T   = (ushort*)alloc((size_t)L_*512*2048*2);
  ushort* pW1T   = (ushort*)alloc((size_t)512*512*2);
  float*  bqkv   = (float*)alloc((size_t)L_*1536*4);
  ushort* h16    = (ushort*)alloc((size_t)M_*H_*2);
  float*  h32    = (float*)alloc((size_t)M_*H_*4);
  ushort* qkv    = (ushort*)alloc((size_t)M_*1536*2);
  ushort* ctx    = (ushort*)alloc((size_t)M_*H_*2);
  ushort* attn16 = (ushort*)alloc((size_t)M_*H_*2);
  float*  attn32 = (float*)alloc((size_t)M_*H_*4);
  ushort* inter  = (ushort*)alloc((size_t)M_*INTER_*2);
  float*  t1     = (float*)alloc((size_t)2*M_*H_*4);
  float*  alpha  = (float*)alloc((size_t)M_*4);
  float*  invsum = (float*)alloc(256);
  float*  outacc = (float*)alloc((size_t)16*B_*H_*4);

  dim3 tb(256);
  TPack tp;
  tp.wq = Wq; tp.wk = Wk; tp.wv = Wv; tp.wo = Wo; tp.pw1 = pW1;
  tp.wqkvT = WqkvT; tp.woT = WoT; tp.pw1T = pW1T;
  transpose512_all<<<dim3(16,16,17), tb, 0, stream>>>(tp);
  transpose_k<<<dim3(64,16,L_), tb, 0, stream>>>(Wi, WiT,    512, 2048, (size_t)512*2048, (size_t)2048*512);
  transpose_k<<<dim3(16,64,L_), tb, 0, stream>>>(Wo2, Wo2T, 2048,  512, (size_t)2048*512, (size_t)512*2048);
  pack_bqkv<<<dim3(L_*1536/256), tb, 0, stream>>>(bq, bk, bv, bqkv);

  embed_ln<<<dim3(M_/2), tb, 0, stream>>>(input_embs, pos, ln_emb_g, ln_emb_b, h16, h32);

  for (int l = 0; l < L_; ++l){
    gemm_bt<0,64><<<dim3(12,64,1), tb, 0, stream>>>(h16, WqkvT + (size_t)l*1536*512, bqkv + l*1536,
                                                    qkv, nullptr, M_, 1536, 512, 512);
    attn_mfma<<<dim3(S_/64, B_*NH_), tb, 0, stream>>>(qkv, mask, ctx);
    gemm_bt<3,64><<<dim3(4,64,2), tb, 0, stream>>>(ctx, WoT + (size_t)l*512*512, bo + l*512,
                                                   nullptr, t1, M_, 512, 512, 256);
    ln_res<<<dim3(M_/2), tb, 0, stream>>>(t1, h32, ln1_g + l*512, ln1_b + l*512, attn16, attn32);
    gemm_bt<1,128><<<dim3(16,32,1), tb, 0, stream>>>(attn16, WiT + (size_t)l*2048*512, bi + l*2048,
                                                     inter, nullptr, M_, 2048, 512, 512);
    gemm_bt<3,64><<<dim3(4,64,2), tb, 0, stream>>>(inter, Wo2T + (size_t)l*512*2048, bo2 + l*512,
                                                   nullptr, t1, M_, 512, 2048, 1024);
    ln_res<<<dim3(M_/2), tb, 0, stream>>>(t1, attn32, ln2_g + l*512, ln2_b + l*512, h16, h32);
  }

  gemm_bt<2,64><<<dim3(4,64,1), tb, 0, stream>>>(h16, pW1T, pb1, ctx, nullptr, M_, 512, 512, 512);
  pool_logit<<<dim3(M_/4), tb, 0, stream>>>(ctx, pW2, pb2, mask, alpha);
  pool_sum<<<dim3(B_), tb, 0, stream>>>(alpha, invsum);
  pool_wsum<<<dim3(16, B_), tb, 0, stream>>>(h32, alpha, outacc);
  pool_final<<<dim3((B_*H_ + 255)/256), tb, 0, stream>>>(outacc, invsum, (float*)d_out);
}

// Round 17
// 389.788 us; speedup vs baseline: 4.2160x; 1.0306x over previous
//
#include <hip/hip_runtime.h>
#include <hip/hip_bf16.h>
#include <math.h>

#define B_ 2
#define S_ 2048
#define H_ 512
#define NH_ 8
#define HD_ 64
#define L_ 4
#define INTER_ 2048
#define W1_ 32
#define M_ (B_*S_)   // 4096

typedef __attribute__((ext_vector_type(8))) short short8v;
typedef __attribute__((ext_vector_type(4))) float f32x4;

__device__ __forceinline__ float b2f(ushort u){ return __uint_as_float(((unsigned)u)<<16); }
__device__ __forceinline__ ushort f2b(float f){
  unsigned u = __float_as_uint(f);
  unsigned r = (u + 0x7fffu + ((u>>16)&1u)) >> 16;
  return (ushort)r;
}
__device__ __forceinline__ void async16(const ushort* g, ushort* l){
  __builtin_amdgcn_global_load_lds(
      (const __attribute__((address_space(1))) unsigned int*)g,
      (__attribute__((address_space(3))) unsigned int*)l, 16, 0, 0);
}

// ---------------------------------------------------------------- prep (ONE dispatch)
struct TPack {
  const float *wq, *wk, *wv, *wo, *pw1, *wi, *wo2, *bq, *bk, *bv;
  ushort *wqkvT, *woT, *pw1T, *wiT, *wo2T;
  float *bqkv;
};

__device__ __forceinline__ void tr_tile(const float* __restrict__ src,
    ushort* __restrict__ dst, int R, int C, int r0, int c0)
{
  __shared__ ushort tile[32][33];
  int tx = threadIdx.x & 31, ty = threadIdx.x >> 5;
  #pragma unroll
  for (int i = 0; i < 4; ++i)
    tile[ty + i*8][tx] = f2b(src[(size_t)(r0 + ty + i*8)*C + c0 + tx]);
  __syncthreads();
  #pragma unroll
  for (int i = 0; i < 4; ++i)
    dst[(size_t)(c0 + ty + i*8)*R + r0 + tx] = tile[tx][ty + i*8];
}

// jobs: [0,4352) 17x 512x512 ; [4352,8448) Wi ; [8448,12544) Wo2 ; [12544,12568) bqkv
__global__ __launch_bounds__(256) void prep_all(TPack p)
{
  int j = blockIdx.x;
  if (j < 4352){
    int z = j >> 8, t = j & 255;
    const float* src; ushort* dst;
    if (z < 12){
      int kind = z >> 2, l = z & 3;
      const float* s3 = (kind == 0) ? p.wq : ((kind == 1) ? p.wk : p.wv);
      src = s3 + (size_t)l*512*512;
      dst = p.wqkvT + (size_t)l*1536*512 + (size_t)kind*512*512;
    } else if (z < 16){
      int l = z - 12; src = p.wo + (size_t)l*512*512; dst = p.woT + (size_t)l*512*512;
    } else { src = p.pw1; dst = p.pw1T; }
    tr_tile(src, dst, 512, 512, (t >> 4)*32, (t & 15)*32);
  } else if (j < 8448){
    int j2 = j - 4352; int z = j2 >> 10, t = j2 & 1023;
    tr_tile(p.wi + (size_t)z*512*2048, p.wiT + (size_t)z*2048*512,
            512, 2048, (t >> 6)*32, (t & 63)*32);
  } else if (j < 12544){
    int j3 = j - 8448; int z = j3 >> 10, t = j3 & 1023;
    tr_tile(p.wo2 + (size_t)z*2048*512, p.wo2T + (size_t)z*512*2048,
            2048, 512, (t >> 4)*32, (t & 15)*32);
  } else {
    int i = (j - 12544)*256 + threadIdx.x;
    int l = i / 1536, n = i % 1536;
    float v = (n < 512) ? p.bq[l*512 + n]
            : (n < 1024 ? p.bk[l*512 + n - 512] : p.bv[l*512 + n - 1024]);
    p.bqkv[i] = v;
  }
}

// ---------------------------------------------------------------- GEMM (B^T)
// BM x 128, BK=64; 4 waves; 2-buffer issue-early pipeline, one barrier/K-step;
// granule-XOR swizzle both sides.
// HARD CONSTRAINTS: N=512 GEMMs need >=2 blocks/CU (split-K z=2); no coop kernels.
template<int EPI, int BM>
__global__ __launch_bounds__(256, (BM == 64) ? 3 : 2) void gemm_bt(
    const ushort* __restrict__ A, const ushort* __restrict__ Bt,
    const float* __restrict__ bias, ushort* __restrict__ o16,
    float* __restrict__ o32, int M, int N, int K, int Klen)
{
  constexpr int ABUF = BM * 64;
  constexpr int BUFE = ABUF + 128 * 64;
  constexpr int MI = BM / 32;
  constexpr int AR = (BM * 8) / 256;
  constexpr int BR = 4;
  __shared__ ushort lds[2 * BUFE];
  const int tid = threadIdx.x;
  const int bm = blockIdx.y * BM, bn = blockIdx.x * 128;
  const int kbeg = blockIdx.z * Klen;
  const int wave = tid >> 6, lane = tid & 63;
  const int wr = (wave >> 1) * (BM / 2), wc = (wave & 1) * 64;
  const int lr = lane & 15, lg = lane >> 4;
  const int l7 = lr & 7;
  f32x4 acc[MI][4] = {};

  const ushort* srcA[AR];
  const ushort* srcB[BR];
  #pragma unroll
  for (int ra = 0; ra < AR; ++ra){
    int s = tid + ra*256; int r = s >> 3, g = s & 7;
    srcA[ra] = A + (size_t)(bm + r) * K + kbeg + ((g ^ (r & 7)) * 8);
  }
  #pragma unroll
  for (int rb = 0; rb < BR; ++rb){
    int s = tid + rb*256; int r = s >> 3, g = s & 7;
    srcB[rb] = Bt + (size_t)(bn + r) * K + kbeg + ((g ^ (r & 7)) * 8);
  }

  const int nIter = Klen >> 6;
  auto issueTile = [&](int t, int buf){
    int k0 = t << 6;
    ushort* dA = &lds[0] + buf*BUFE + tid*8;
    ushort* dB = &lds[0] + buf*BUFE + ABUF + tid*8;
    #pragma unroll
    for (int ra = 0; ra < AR; ++ra) async16(srcA[ra] + k0, dA + ra*2048);
    #pragma unroll
    for (int rb = 0; rb < BR; ++rb) async16(srcB[rb] + k0, dB + rb*2048);
  };

  issueTile(0, 0);
  asm volatile("s_waitcnt vmcnt(0)" ::: "memory");
  __builtin_amdgcn_s_barrier();

  int cur = 0;
  for (int t = 0; t < nIter; ++t){
    if (t + 1 < nIter) issueTile(t + 1, cur ^ 1);
    const ushort* bufp = &lds[0] + cur*BUFE;
    #pragma unroll
    for (int ks = 0; ks < 2; ++ks){
      short8v af[MI], bfr[4];
      #pragma unroll
      for (int mi = 0; mi < MI; ++mi){
        int R = wr + mi*16 + lr;
        af[mi] = *(const short8v*)(bufp + R*64 + (((ks*4 + lg) ^ l7) * 8));
      }
      #pragma unroll
      for (int nj = 0; nj < 4; ++nj){
        int Rb = wc + nj*16 + lr;
        bfr[nj] = *(const short8v*)(bufp + ABUF + Rb*64 + (((ks*4 + lg) ^ l7) * 8));
      }
      #pragma unroll
      for (int mi = 0; mi < MI; ++mi)
        #pragma unroll
        for (int nj = 0; nj < 4; ++nj)
          acc[mi][nj] = __builtin_amdgcn_mfma_f32_16x16x32_bf16(af[mi], bfr[nj], acc[mi][nj], 0, 0, 0);
    }
    asm volatile("s_waitcnt vmcnt(0)" ::: "memory");
    __builtin_amdgcn_s_barrier();
    cur ^= 1;
  }

  const float bscale = (blockIdx.z == 0) ? 1.0f : 0.0f;
  #pragma unroll
  for (int mi = 0; mi < MI; ++mi){
    #pragma unroll
    for (int nj = 0; nj < 4; ++nj){
      int col = bn + wc + nj*16 + lr;
      float bv = bias[col] * bscale;
      #pragma unroll
      for (int j = 0; j < 4; ++j){
        int row = bm + wr + mi*16 + lg*4 + j;
        float v = acc[mi][nj][j] + bv;
        if (EPI == 1) v = 0.5f * v * (1.0f + erff(v * 0.70710678118654752f));
        if (EPI == 2) v = tanhf(v);
        if (EPI == 3) o32[(size_t)blockIdx.z*M*N + (size_t)row * N + col] = v;
        else          o16[(size_t)row * N + col] = f2b(v);
      }
    }
  }
}

// ---------------------------------------------------------------- LayerNorm (2 rows/block)
__device__ __forceinline__ void ln_stats2(float a0, float a1, float b0, float b1,
    float* red, float& meanA, float& rstdA, float& meanB, float& rstdB)
{
  int tid = threadIdx.x, wave = tid >> 6, lane = tid & 63;
  float smA = a0 + a1, sqA = a0*a0 + a1*a1;
  float smB = b0 + b1, sqB = b0*b0 + b1*b1;
  #pragma unroll
  for (int o = 32; o > 0; o >>= 1){
    smA += __shfl_xor(smA, o); sqA += __shfl_xor(sqA, o);
    smB += __shfl_xor(smB, o); sqB += __shfl_xor(sqB, o);
  }
  if (lane == 0){
    red[wave] = smA; red[4 + wave] = sqA;
    red[8 + wave] = smB; red[12 + wave] = sqB;
  }
  __syncthreads();
  float SA = red[0]+red[1]+red[2]+red[3], QA = red[4]+red[5]+red[6]+red[7];
  float SB = red[8]+red[9]+red[10]+red[11], QB = red[12]+red[13]+red[14]+red[15];
  meanA = SA * (1.0f/512.0f);
  float vA = QA * (1.0f/512.0f) - meanA*meanA; if (vA < 0.f) vA = 0.f;
  rstdA = rsqrtf(vA + 1e-12f);
  meanB = SB * (1.0f/512.0f);
  float vB = QB * (1.0f/512.0f) - meanB*meanB; if (vB < 0.f) vB = 0.f;
  rstdB = rsqrtf(vB + 1e-12f);
}

__global__ __launch_bounds__(256) void embed_ln(const float* __restrict__ x,
    const float* __restrict__ pos, const float* __restrict__ g,
    const float* __restrict__ bb, ushort* __restrict__ out16, float* __restrict__ out32)
{
  __shared__ float red[16];
  int rowA = blockIdx.x*2, rowB = rowA + 1, tid = threadIdx.x;
  int sA = rowA & (S_ - 1), sB = rowB & (S_ - 1);
  const size_t baseA = (size_t)rowA*H_ + tid*2;
  const size_t baseB = (size_t)rowB*H_ + tid*2;
  float2 xA = *(const float2*)(x + baseA);
  float2 pA = *(const float2*)(pos + (size_t)sA*H_ + tid*2);
  float2 xB = *(const float2*)(x + baseB);
  float2 pB = *(const float2*)(pos + (size_t)sB*H_ + tid*2);
  float a0 = xA.x + pA.x, a1 = xA.y + pA.y;
  float b0 = xB.x + pB.x, b1 = xB.y + pB.y;
  float mA, rA, mB, rB;
  ln_stats2(a0, a1, b0, b1, red, mA, rA, mB, rB);
  float2 gv = *(const float2*)(g + tid*2);
  float2 bv = *(const float2*)(bb + tid*2);
  float ra0 = (a0 - mA)*rA*gv.x + bv.x, ra1 = (a1 - mA)*rA*gv.y + bv.y;
  float rb0 = (b0 - mB)*rB*gv.x + bv.x, rb1 = (b1 - mB)*rB*gv.y + bv.y;
  ushort2 oA; oA.x = f2b(ra0); oA.y = f2b(ra1);
  ushort2 oB; oB.x = f2b(rb0); oB.y = f2b(rb1);
  *(ushort2*)(out16 + baseA) = oA;
  *(ushort2*)(out16 + baseB) = oB;
  float2 fA; fA.x = ra0; fA.y = ra1;
  float2 fB; fB.x = rb0; fB.y = rb1;
  *(float2*)(out32 + baseA) = fA;
  *(float2*)(out32 + baseB) = fB;
}

__global__ __launch_bounds__(256) void ln_res(const float* __restrict__ t,
    const float* __restrict__ res, const float* __restrict__ g,
    const float* __restrict__ bb, ushort* __restrict__ out16, float* __restrict__ out32)
{
  __shared__ float red[16];
  int rowA = blockIdx.x*2, rowB = rowA + 1, tid = threadIdx.x;
  const size_t MN = (size_t)M_*H_;
  const size_t baseA = (size_t)rowA*H_ + tid*2;
  const size_t baseB = (size_t)rowB*H_ + tid*2;
  float2 tA0 = *(const float2*)(t + baseA);
  float2 tA1 = *(const float2*)(t + MN + baseA);
  float2 rAv = *(const float2*)(res + baseA);
  float2 tB0 = *(const float2*)(t + baseB);
  float2 tB1 = *(const float2*)(t + MN + baseB);
  float2 rBv = *(const float2*)(res + baseB);
  float a0 = tA0.x + tA1.x + rAv.x, a1 = tA0.y + tA1.y + rAv.y;
  float b0 = tB0.x + tB1.x + rBv.x, b1 = tB0.y + tB1.y + rBv.y;
  float mA, rA, mB, rB;
  ln_stats2(a0, a1, b0, b1, red, mA, rA, mB, rB);
  float2 gv = *(const float2*)(g + tid*2);
  float2 bv = *(const float2*)(bb + tid*2);
  float ra0 = (a0 - mA)*rA*gv.x + bv.x, ra1 = (a1 - mA)*rA*gv.y + bv.y;
  float rb0 = (b0 - mB)*rB*gv.x + bv.x, rb1 = (b1 - mB)*rB*gv.y + bv.y;
  ushort2 oA; oA.x = f2b(ra0); oA.y = f2b(ra1);
  ushort2 oB; oB.x = f2b(rb0); oB.y = f2b(rb1);
  *(ushort2*)(out16 + baseA) = oA;
  *(ushort2*)(out16 + baseB) = oB;
  float2 fA; fA.x = ra0; fA.y = ra1;
  float2 fB; fB.x = rb0; fB.y = rb1;
  *(float2*)(out32 + baseA) = fA;
  *(float2*)(out32 + baseB) = fB;
}

// ---------------------------------------------------------------- attention (MFMA)
__global__ __launch_bounds__(256) void attn_mfma(const ushort* __restrict__ qkv,
    const float* __restrict__ mask, ushort* __restrict__ ctx)
{
  __shared__ ushort K_lin[128*64];
  __shared__ ushort Vt[64][136];
  __shared__ ushort P_lds[64][136];
  __shared__ float  kb[128];

  const int tid = threadIdx.x, wave = tid >> 6, lane = tid & 63;
  const int hh = blockIdx.y & (NH_ - 1), b = blockIdx.y >> 3;
  const int s0 = blockIdx.x * 64;
  const size_t rb = (size_t)b * S_;

  #pragma unroll
  for (int r = 0; r < 4; ++r){
    int s = tid + r*256;
    int row = s >> 3, g = s & 7;
    int j = s0 - 32 + row;
    int jc = min(max(j, 0), S_ - 1);
    const ushort* src = qkv + (rb + jc)*1536 + 512 + hh*64 + ((g ^ (row & 7)) * 8);
    async16(src, &K_lin[0] + tid*8 + r*2048);
  }
  const int ch = tid & 7, rr = tid >> 3;
  #pragma unroll
  for (int it = 0; it < 2; ++it){
    int c0 = rr*2 + it*64;
    short8v vv[2];
    #pragma unroll
    for (int p = 0; p < 2; ++p){
      int c = c0 + p;
      int j = s0 - 32 + c;
      int jc = min(max(j, 0), S_ - 1);
      vv[p] = *(const short8v*)(qkv + (rb + jc)*1536 + 1024 + hh*64 + ch*8);
    }
    #pragma unroll
    for (int t = 0; t < 8; ++t){
      int tt = (t + ch) & 7;
      int d = ch*8 + tt;
      ushort2 w; w.x = (ushort)vv[0][tt]; w.y = (ushort)vv[1][tt];
      *(ushort2*)(&Vt[d][c0]) = w;
    }
  }
  if (tid < 128){
    int j = s0 - 32 + tid;
    kb[tid] = (j >= 0 && j < S_) ? (1.0f - mask[rb + j]) * (-10000.0f) : -1e30f;
  }
  __syncthreads();

  const int wq0 = wave * 16;
  const int lr = lane & 15, lg = lane >> 4, lk = lg * 8;
  const int l7 = lr & 7;

  const ushort* qbase = qkv + (rb + s0 + wq0 + lr) * 1536 + hh*64;
  short8v aq0 = *(const short8v*)(qbase + lk);
  short8v aq1 = *(const short8v*)(qbase + 32 + lk);

  f32x4 sacc[8];
  #pragma unroll
  for (int cn = 0; cn < 8; ++cn){
    int row = cn*16 + lr;
    short8v bk0 = *(const short8v*)(&K_lin[row*64 + ((lg ^ l7) * 8)]);
    short8v bk1 = *(const short8v*)(&K_lin[row*64 + (((4 + lg) ^ l7) * 8)]);
    f32x4 z = {0.f, 0.f, 0.f, 0.f};
    z = __builtin_amdgcn_mfma_f32_16x16x32_bf16(aq0, bk0, z, 0, 0, 0);
    z = __builtin_amdgcn_mfma_f32_16x16x32_bf16(aq1, bk1, z, 0, 0, 0);
    sacc[cn] = z;
  }
  #pragma unroll
  for (int jr = 0; jr < 4; ++jr){
    const int R = wq0 + lg*4 + jr;
    float v[8], mx = -1e30f;
    #pragma unroll
    for (int cn = 0; cn < 8; ++cn){
      int c = cn*16 + lr;
      float sc = sacc[cn][jr] * 0.125f + kb[c];
      if (c < R || c > R + 64) sc = -1e30f;
      v[cn] = sc;
      mx = fmaxf(mx, sc);
    }
    #pragma unroll
    for (int o = 1; o < 16; o <<= 1) mx = fmaxf(mx, __shfl_xor(mx, o));
    float sum = 0.f;
    #pragma unroll
    for (int cn = 0; cn < 8; ++cn){ v[cn] = __expf(v[cn] - mx); sum += v[cn]; }
    #pragma unroll
    for (int o = 1; o < 16; o <<= 1) sum += __shfl_xor(sum, o);
    float qm = mask[rb + s0 + R];
    float inv = ((qm < 0.999f) ? 0.0f : 1.0f) / sum;
    #pragma unroll
    for (int cn = 0; cn < 8; ++cn)
      P_lds[R][cn*16 + lr] = f2b(v[cn] * inv);
  }
  short8v ap[4];
  #pragma unroll
  for (int ks = 0; ks < 4; ++ks)
    ap[ks] = *(const short8v*)(&P_lds[wq0 + lr][ks*32 + lk]);
  #pragma unroll
  for (int dn = 0; dn < 4; ++dn){
    f32x4 z = {0.f, 0.f, 0.f, 0.f};
    #pragma unroll
    for (int ks = 0; ks < 4; ++ks){
      short8v bv = *(const short8v*)(&Vt[dn*16 + lr][ks*32 + lk]);
      z = __builtin_amdgcn_mfma_f32_16x16x32_bf16(ap[ks], bv, z, 0, 0, 0);
    }
    #pragma unroll
    for (int jr = 0; jr < 4; ++jr){
      int R = wq0 + lg*4 + jr;
      ctx[(rb + s0 + R)*H_ + hh*64 + dn*16 + lr] = f2b(z[jr]);
    }
  }
}

// ---------------------------------------------------------------- pooling
__global__ __launch_bounds__(256) void pool_logit(const ushort* __restrict__ e,
    const float* __restrict__ w2, const float* __restrict__ b2p,
    const float* __restrict__ mask, float* __restrict__ alpha)
{
  int tid = threadIdx.x, wave = tid >> 6, lane = tid & 63;
  int r = blockIdx.x * 4 + wave;
  short8v ev = *(const short8v*)(e + (size_t)r*H_ + lane*8);
  float sacc = 0.f;
  #pragma unroll
  for (int j = 0; j < 8; ++j) sacc += b2f((ushort)ev[j]) * w2[lane*8 + j];
  #pragma unroll
  for (int o = 32; o > 0; o >>= 1) sacc += __shfl_xor(sacc, o);
  if (lane == 0){
    float logit = sacc + b2p[0];
    alpha[r] = __expf(logit) * mask[r];
  }
}

__global__ __launch_bounds__(256) void pool_wsum(const float* __restrict__ x,
    const float* __restrict__ alpha, float* __restrict__ out_acc)
{
  int chunk = blockIdx.x, b = blockIdx.y, tid = threadIdx.x;
  int s0 = chunk * 128;
  int c0 = tid * 2;
  float a0 = 0.f, a1 = 0.f;
  for (int i = 0; i < 128; ++i){
    int srow = s0 + i;
    float al = alpha[b*S_ + srow];
    float2 xv = *(const float2*)(x + (size_t)(b*S_ + srow)*H_ + c0);
    a0 += xv.x * al;
    a1 += xv.y * al;
  }
  float2 o; o.x = a0; o.y = a1;
  *(float2*)(out_acc + (size_t)chunk*B_*H_ + b*H_ + c0) = o;
}

// merged: per-block alpha reduce (invsum) + chunk-sum + final scale
__global__ __launch_bounds__(256) void pool_final(const float* __restrict__ out_acc,
    const float* __restrict__ alpha, float* __restrict__ out)
{
  __shared__ float red[4];
  int i = blockIdx.x * 256 + threadIdx.x;
  int b = i >> 9;
  int tid = threadIdx.x, wave = tid >> 6, lane = tid & 63;
  // reduce alpha[b*S_ .. b*S_+S_) within this block (all threads same b)
  float s = 0.f;
  for (int k = tid; k < S_; k += 256) s += alpha[b*S_ + k];
  #pragma unroll
  for (int o = 32; o > 0; o >>= 1) s += __shfl_xor(s, o);
  if (lane == 0) red[wave] = s;
  __syncthreads();
  float invsum = 1.0f / (red[0] + red[1] + red[2] + red[3] + 1e-8f);
  if (i < B_*H_){
    float acc = 0.f;
    #pragma unroll
    for (int c = 0; c < 16; ++c) acc += out_acc[(size_t)c*B_*H_ + i];
    out[i] = acc * invsum;
  }
}

// ---------------------------------------------------------------- launch
extern "C" void kernel_launch(void* const* d_in, const int* in_sizes, int n_in,
                              void* d_out, int out_size, void* d_ws, size_t ws_size,
                              hipStream_t stream)
{
  const float* input_embs = (const float*)d_in[0];
  const float* mask       = (const float*)d_in[1];
  const float* pos        = (const float*)d_in[2];
  const float* ln_emb_g   = (const float*)d_in[3];
  const float* ln_emb_b   = (const float*)d_in[4];
  const float* Wq  = (const float*)d_in[5];
  const float* bq  = (const float*)d_in[6];
  const float* Wk  = (const float*)d_in[7];
  const float* bk  = (const float*)d_in[8];
  const float* Wv  = (const float*)d_in[9];
  const float* bv  = (const float*)d_in[10];
  const float* Wo  = (const float*)d_in[11];
  const float* bo  = (const float*)d_in[12];
  const float* ln1_g = (const float*)d_in[13];
  const float* ln1_b = (const float*)d_in[14];
  const float* Wi  = (const float*)d_in[15];
  const float* bi  = (const float*)d_in[16];
  const float* Wo2 = (const float*)d_in[17];
  const float* bo2 = (const float*)d_in[18];
  const float* ln2_g = (const float*)d_in[19];
  const float* ln2_b = (const float*)d_in[20];
  const float* pW1 = (const float*)d_in[21];
  const float* pb1 = (const float*)d_in[22];
  const float* pW2 = (const float*)d_in[23];
  const float* pb2 = (const float*)d_in[24];

  char* ws = (char*)d_ws;
  size_t off = 0;
  auto alloc = [&](size_t bytes)->char*{
    char* p = ws + off; off += (bytes + 255) & ~(size_t)255; return p;
  };
  ushort* WqkvT  = (ushort*)alloc((size_t)L_*1536*512*2);
  ushort* WoT    = (ushort*)alloc((size_t)L_*512*512*2);
  ushort* WiT    = (ushort*)alloc((size_t)L_*2048*512*2);
  ushort* Wo2T   = (ushort*)alloc((size_t)L_*512*2048*2);
  ushort* pW1T   = (ushort*)alloc((size_t)512*512*2);
  float*  bqkv   = (float*)alloc((size_t)L_*1536*4);
  ushort* h16    = (ushort*)alloc((size_t)M_*H_*2);
  float*  h32    = (float*)alloc((size_t)M_*H_*4);
  ushort* qkv    = (ushort*)alloc((size_t)M_*1536*2);
  ushort* ctx    = (ushort*)alloc((size_t)M_*H_*2);
  ushort* attn16 = (ushort*)alloc((size_t)M_*H_*2);
  float*  attn32 = (float*)alloc((size_t)M_*H_*4);
  ushort* inter  = (ushort*)alloc((size_t)M_*INTER_*2);
  float*  t1     = (float*)alloc((size_t)2*M_*H_*4);
  float*  alpha  = (float*)alloc((size_t)M_*4);
  float*  outacc = (float*)alloc((size_t)16*B_*H_*4);

  dim3 tb(256);
  TPack tp;
  tp.wq = Wq; tp.wk = Wk; tp.wv = Wv; tp.wo = Wo; tp.pw1 = pW1;
  tp.wi = Wi; tp.wo2 = Wo2; tp.bq = bq; tp.bk = bk; tp.bv = bv;
  tp.wqkvT = WqkvT; tp.woT = WoT; tp.pw1T = pW1T; tp.wiT = WiT; tp.wo2T = Wo2T;
  tp.bqkv = bqkv;
  prep_all<<<dim3(12568), tb, 0, stream>>>(tp);

  embed_ln<<<dim3(M_/2), tb, 0, stream>>>(input_embs, pos, ln_emb_g, ln_emb_b, h16, h32);

  for (int l = 0; l < L_; ++l){
    gemm_bt<0,64><<<dim3(12,64,1), tb, 0, stream>>>(h16, WqkvT + (size_t)l*1536*512, bqkv + l*1536,
                                                    qkv, nullptr, M_, 1536, 512, 512);
    attn_mfma<<<dim3(S_/64, B_*NH_), tb, 0, stream>>>(qkv, mask, ctx);
    gemm_bt<3,64><<<dim3(4,64,2), tb, 0, stream>>>(ctx, WoT + (size_t)l*512*512, bo + l*512,
                                                   nullptr, t1, M_, 512, 512, 256);
    ln_res<<<dim3(M_/2), tb, 0, stream>>>(t1, h32, ln1_g + l*512, ln1_b + l*512, attn16, attn32);
    gemm_bt<1,128><<<dim3(16,32,1), tb, 0, stream>>>(attn16, WiT + (size_t)l*2048*512, bi + l*2048,
                                                     inter, nullptr, M_, 2048, 512, 512);
    gemm_bt<3,64><<<dim3(4,64,2), tb, 0, stream>>>(inter, Wo2T + (size_t)l*512*2048, bo2 + l*512,
                                                   nullptr, t1, M_, 512, 2048, 1024);
    ln_res<<<dim3(M_/2), tb, 0, stream>>>(t1, attn32, ln2_g + l*512, ln2_b + l*512, h16, h32);
  }

  gemm_bt<2,64><<<dim3(4,64,1), tb, 0, stream>>>(h16, pW1T, pb1, ctx, nullptr, M_, 512, 512, 512);
  pool_logit<<<dim3(M_/4), tb, 0, stream>>>(ctx, pW2, pb2, mask, alpha);
  pool_wsum<<<dim3(16, B_), tb, 0, stream>>>(h32, alpha, outacc);
  pool_final<<<dim3((B_*H_ + 255)/256), tb, 0, stream>>>(outacc, alpha, (float*)d_out);
}